// Round 1
// baseline (1175.018 us; speedup 1.0000x reference)
//
#include <hip/hip_runtime.h>
#include <stdint.h>

#define NQ 49      // queries (patch tokens)
#define MT 50      // tokens incl cls (keys)
#define NH 8
#define HD 32
#define NW 64
#define BWIN 4096  // total windows

typedef __attribute__((ext_vector_type(8))) short short8;
typedef __attribute__((ext_vector_type(4))) float f32x4;
typedef __attribute__((ext_vector_type(4))) uint32_t u32x4;

__device__ __forceinline__ uint32_t f2u(float x){ union{float f;uint32_t u;}c; c.f=x; return c.u; }
__device__ __forceinline__ float u2f(uint32_t u){ union{float f;uint32_t u;}c; c.u=u; return c.f; }
// round-to-nearest-even fp32 -> bf16 bits (finite inputs only)
__device__ __forceinline__ uint32_t bf16rn(float x){
  uint32_t u = f2u(x);
  return (u + 0x7fffu + ((u >> 16) & 1u)) >> 16;
}
// split x ~= hi + lo (both bf16), error ~2^-18 * |x|
__device__ __forceinline__ void bsplit(float x, uint32_t& hi, uint32_t& lo){
  hi = bf16rn(x);
  float hf = u2f(hi << 16);
  lo = bf16rn(x - hf);
}

__global__ __launch_bounds__(64, 2)
void winattn_kernel(const float* __restrict__ qkv,
                    const float* __restrict__ mask,
                    const float* __restrict__ bias_table,
                    const int*   __restrict__ rel_index,
                    float* __restrict__ out)
{
  // P (unnormalized probs), packed hi|lo bf16 per element. 64 rows x stride 68.
  __shared__ uint32_t sP[64 * 68];

  const int id   = blockIdx.x;
  const int b    = id >> 3;
  const int h    = id & 7;
  const int w    = b & (NW - 1);
  const int lane = threadIdx.x;   // 0..63
  const int ln   = lane & 15;
  const int qd   = lane >> 4;     // quad 0..3

  const float* base = qkv + (size_t)b * (MT * 3 * 256);

  // ================= Phase 1: Q,K fragments (global -> regs, bf16 hi/lo) ====
  short8 qh[4], ql[4], kh[4], kl[4];
  const float scale = 0.17677669529663687f;  // 1/sqrt(32)

#pragma unroll
  for (int t = 0; t < 4; ++t) {
    int m   = 16 * t + ln;                    // query row 0..63
    int tok = (m < NQ ? m : NQ - 1) + 1;      // clamp; +1 skips cls token
    const float* p = base + (size_t)tok * 768 + h * HD + qd * 8;
    f32x4 e0 = *(const f32x4*)p;
    f32x4 e1 = *(const f32x4*)(p + 4);
#pragma unroll
    for (int j = 0; j < 8; ++j) {
      float x = (j < 4 ? e0[j] : e1[j - 4]) * scale;
      uint32_t hi, lo; bsplit(x, hi, lo);
      qh[t][j] = (short)(unsigned short)hi;
      ql[t][j] = (short)(unsigned short)lo;
    }
  }
#pragma unroll
  for (int u = 0; u < 4; ++u) {
    int n    = 16 * u + ln;                   // key col 0..63
    int ktok = (n < MT ? n : MT - 1);
    const float* p = base + (size_t)ktok * 768 + 256 + h * HD + qd * 8;
    f32x4 e0 = *(const f32x4*)p;
    f32x4 e1 = *(const f32x4*)(p + 4);
#pragma unroll
    for (int j = 0; j < 8; ++j) {
      float x = (j < 4 ? e0[j] : e1[j - 4]);
      uint32_t hi, lo; bsplit(x, hi, lo);
      kh[u][j] = (short)(unsigned short)hi;
      kl[u][j] = (short)(unsigned short)lo;
    }
  }

  // ================= QK^T via MFMA (3-term hi/lo expansion) =================
  f32x4 S[4][4];
#pragma unroll
  for (int t = 0; t < 4; ++t) {
#pragma unroll
    for (int u = 0; u < 4; ++u) {
      f32x4 a = {0.f, 0.f, 0.f, 0.f};
      a = __builtin_amdgcn_mfma_f32_16x16x32_bf16(qh[t], kh[u], a, 0, 0, 0);
      a = __builtin_amdgcn_mfma_f32_16x16x32_bf16(qh[t], kl[u], a, 0, 0, 0);
      a = __builtin_amdgcn_mfma_f32_16x16x32_bf16(ql[t], kh[u], a, 0, 0, 0);
      S[t][u] = a;
    }
  }

  // ================= bias + mask + column masking ===========================
#pragma unroll
  for (int t = 0; t < 4; ++t) {
#pragma unroll
    for (int r = 0; r < 4; ++r) {
      int i = 16 * t + 4 * qd + r;           // query row (C/D layout)
#pragma unroll
      for (int u = 0; u < 4; ++u) {
        int j = 16 * u + ln;                 // key col
        if (j >= MT) {
          S[t][u][r] = -1e30f;
        } else if (i < NQ) {
          float am = mask[(w * NQ + i) * MT + j];
          if (j > 0) {
            int idx = rel_index[i * NQ + (j - 1)];
            am += bias_table[idx * NH + h];
          }
          S[t][u][r] += am;
        }
      }
    }
  }

  // ================= softmax in registers (16-lane shuffles) ================
  float rsumv[4][4];
#pragma unroll
  for (int t = 0; t < 4; ++t) {
#pragma unroll
    for (int r = 0; r < 4; ++r) {
      float mx = fmaxf(fmaxf(S[t][0][r], S[t][1][r]), fmaxf(S[t][2][r], S[t][3][r]));
#pragma unroll
      for (int s = 1; s < 16; s <<= 1) mx = fmaxf(mx, __shfl_xor(mx, s, 16));
      int row = 16 * t + 4 * qd + r;
      float sum = 0.f;
#pragma unroll
      for (int u = 0; u < 4; ++u) {
        float p = exp2f((S[t][u][r] - mx) * 1.4426950408889634f);
        sum += p;
        uint32_t hi, lo; bsplit(p, hi, lo);
        sP[row * 68 + 16 * u + ln] = (hi << 16) | lo;
      }
#pragma unroll
      for (int s = 1; s < 16; s <<= 1) sum += __shfl_xor(sum, s, 16);
      rsumv[t][r] = sum;
    }
  }
  __syncthreads();

  // ================= V fragments (global, clamped+zeroed padding) ===========
  short8 vh[2][2], vl[2][2];   // [k-iter][d-tile]
#pragma unroll
  for (int kt = 0; kt < 2; ++kt) {
#pragma unroll
    for (int u2 = 0; u2 < 2; ++u2) {
#pragma unroll
      for (int j = 0; j < 8; ++j) {
        int k  = 32 * kt + 8 * qd + j;
        int d  = 16 * u2 + ln;
        int kc = (k < MT ? k : MT - 1);
        float x = base[(size_t)kc * 768 + 512 + h * HD + d];
        if (k >= MT) x = 0.f;
        uint32_t hi, lo; bsplit(x, hi, lo);
        vh[kt][u2][j] = (short)(unsigned short)hi;
        vl[kt][u2][j] = (short)(unsigned short)lo;
      }
    }
  }

  // ================= PV via MFMA ============================================
  f32x4 O[4][2];
#pragma unroll
  for (int t = 0; t < 4; ++t)
#pragma unroll
    for (int u2 = 0; u2 < 2; ++u2) O[t][u2] = (f32x4){0.f, 0.f, 0.f, 0.f};

#pragma unroll
  for (int kt = 0; kt < 2; ++kt) {
#pragma unroll
    for (int t = 0; t < 4; ++t) {
      const uint32_t* pp = &sP[(16 * t + ln) * 68 + 32 * kt + 8 * qd];
      u32x4 w0 = *(const u32x4*)pp;
      u32x4 w1 = *(const u32x4*)(pp + 4);
      short8 ph, pl;
#pragma unroll
      for (int j = 0; j < 8; ++j) {
        uint32_t wv = (j < 4 ? w0[j] : w1[j - 4]);
        ph[j] = (short)(unsigned short)(wv >> 16);
        pl[j] = (short)(unsigned short)(wv & 0xffffu);
      }
#pragma unroll
      for (int u2 = 0; u2 < 2; ++u2) {
        f32x4 a = O[t][u2];
        a = __builtin_amdgcn_mfma_f32_16x16x32_bf16(ph, vh[kt][u2], a, 0, 0, 0);
        a = __builtin_amdgcn_mfma_f32_16x16x32_bf16(pl, vh[kt][u2], a, 0, 0, 0);
        a = __builtin_amdgcn_mfma_f32_16x16x32_bf16(ph, vl[kt][u2], a, 0, 0, 0);
        O[t][u2] = a;
      }
    }
  }

  // ================= epilogue: normalize + store ============================
#pragma unroll
  for (int t = 0; t < 4; ++t) {
#pragma unroll
    for (int r = 0; r < 4; ++r) {
      int row = 16 * t + 4 * qd + r;
      if (row >= NQ) continue;
      float inv = 1.0f / rsumv[t][r];
#pragma unroll
      for (int u2 = 0; u2 < 2; ++u2) {
        int d = 16 * u2 + ln;
        out[(((size_t)b * NQ + row) * NH + h) * HD + d] = O[t][u2][r] * inv;
      }
    }
  }
}

extern "C" void kernel_launch(void* const* d_in, const int* in_sizes, int n_in,
                              void* d_out, int out_size, void* d_ws, size_t ws_size,
                              hipStream_t stream) {
  (void)in_sizes; (void)n_in; (void)d_ws; (void)ws_size; (void)out_size;
  const float* qkv        = (const float*)d_in[0];
  const float* mask       = (const float*)d_in[1];
  const float* bias_table = (const float*)d_in[2];
  const int*   rel_index  = (const int*)d_in[3];
  float* out = (float*)d_out;

  dim3 grid(BWIN * NH);   // one wave per (window, head)
  winattn_kernel<<<grid, 64, 0, stream>>>(qkv, mask, bias_table, rel_index, out);
}

// Round 2
// 944.721 us; speedup vs baseline: 1.2438x; 1.2438x over previous
//
#include <hip/hip_runtime.h>
#include <stdint.h>

#define NQ 49      // queries (patch tokens)
#define MT 50      // tokens incl cls (keys)
#define NH 8
#define HD 32
#define NW 64
#define BWIN 4096  // total windows
#define M2TOT (NW*NH*NQ*MT)   // fused mask+bias tensor elements

typedef __attribute__((ext_vector_type(8))) short short8;
typedef __attribute__((ext_vector_type(4))) float f32x4;

__device__ __forceinline__ uint32_t f2u(float x){ union{float f;uint32_t u;}c; c.f=x; return c.u; }
__device__ __forceinline__ float u2f(uint32_t u){ union{float f;uint32_t u;}c; c.u=u; return c.f; }
// round-to-nearest-even fp32 -> bf16 bits (finite inputs only)
__device__ __forceinline__ uint32_t bf16rn(float x){
  uint32_t u = f2u(x);
  return (u + 0x7fffu + ((u >> 16) & 1u)) >> 16;
}
// split x ~= hi + lo (both bf16), error ~2^-18 * |x|
__device__ __forceinline__ void bsplit(float x, uint32_t& hi, uint32_t& lo){
  hi = bf16rn(x);
  lo = bf16rn(x - u2f(hi << 16));
}

// ============ kernel 1: fuse additive mask + relative-position bias =========
// M2[w][h][i][j] = mask[w,i,j] + (j>0 ? bias_table[rel_index[i,j-1], h] : 0)
__global__ void fuse_mb(const float* __restrict__ mask,
                        const float* __restrict__ bias_table,
                        const int*   __restrict__ rel_index,
                        float* __restrict__ M2)
{
  int idx = blockIdx.x * 256 + threadIdx.x;
  if (idx >= M2TOT) return;
  int j  = idx % MT;
  int t  = idx / MT;
  int i  = t % NQ;
  int t2 = t / NQ;
  int h  = t2 % NH;
  int w  = t2 / NH;
  float v = mask[(w * NQ + i) * MT + j];
  if (j > 0) v += bias_table[rel_index[i * NQ + (j - 1)] * NH + h];
  M2[idx] = v;
}

// ============ kernel 2: attention, 1 wave per (window, head), 2 heads/block =
__global__ __launch_bounds__(128, 4)
void winattn_kernel(const float* __restrict__ qkv,
                    const float* __restrict__ M2,
                    float* __restrict__ out)
{
  // P (unnormalized probs) as bf16, 64x64 per wave, XOR-swizzled 16B chunks
  // (conflict-free b128 reads, no padding needed).
  __shared__ unsigned short sP[2][64 * 64];

  const int wv   = threadIdx.x >> 6;      // wave in block (= head parity)
  const int lane = threadIdx.x & 63;
  const int ln   = lane & 15;
  const int qd   = lane >> 4;             // quad 0..3

  const int id = blockIdx.x;
  const int b  = id >> 2;
  const int h  = ((id & 3) << 1) | wv;
  const int w  = b & (NW - 1);

  const float* base = qkv + (size_t)b * (MT * 3 * 256);
  const float scale = 0.17677669529663687f;  // 1/sqrt(32)

  // ---- Q, K fragments: global -> regs, bf16 hi/lo split --------------------
  short8 qh[4], ql[4], kh[4], kl[4];
#pragma unroll
  for (int t = 0; t < 4; ++t) {
    int m   = 16 * t + ln;
    int tok = (m < NQ ? m : NQ - 1) + 1;       // +1 skips cls token
    const float* p = base + (size_t)tok * 768 + h * HD + qd * 8;
    f32x4 e0 = *(const f32x4*)p;
    f32x4 e1 = *(const f32x4*)(p + 4);
#pragma unroll
    for (int j = 0; j < 8; ++j) {
      float x = (j < 4 ? e0[j] : e1[j - 4]) * scale;
      uint32_t hi, lo; bsplit(x, hi, lo);
      qh[t][j] = (short)(unsigned short)hi;
      ql[t][j] = (short)(unsigned short)lo;
    }
  }
#pragma unroll
  for (int u = 0; u < 4; ++u) {
    int n    = 16 * u + ln;
    int ktok = (n < MT ? n : MT - 1);
    const float* p = base + (size_t)ktok * 768 + 256 + h * HD + qd * 8;
    f32x4 e0 = *(const f32x4*)p;
    f32x4 e1 = *(const f32x4*)(p + 4);
#pragma unroll
    for (int j = 0; j < 8; ++j) {
      float x = (j < 4 ? e0[j] : e1[j - 4]);
      uint32_t hi, lo; bsplit(x, hi, lo);
      kh[u][j] = (short)(unsigned short)hi;
      kl[u][j] = (short)(unsigned short)lo;
    }
  }

  // ---- QK^T via MFMA, 3-term hi/lo expansion (fp32-like accuracy) ----------
  f32x4 S[4][4];
#pragma unroll
  for (int t = 0; t < 4; ++t) {
#pragma unroll
    for (int u = 0; u < 4; ++u) {
      f32x4 a = {0.f, 0.f, 0.f, 0.f};
      a = __builtin_amdgcn_mfma_f32_16x16x32_bf16(qh[t], kh[u], a, 0, 0, 0);
      a = __builtin_amdgcn_mfma_f32_16x16x32_bf16(qh[t], kl[u], a, 0, 0, 0);
      a = __builtin_amdgcn_mfma_f32_16x16x32_bf16(ql[t], kh[u], a, 0, 0, 0);
      S[t][u] = a;
    }
  }

  // ---- add fused mask+bias (single coalesced load per score) ---------------
  const float* mrow = M2 + ((size_t)(w * NH + h) * NQ) * MT;
#pragma unroll
  for (int t = 0; t < 4; ++t) {
#pragma unroll
    for (int r = 0; r < 4; ++r) {
      int i = 16 * t + 4 * qd + r;           // query row (C/D layout)
#pragma unroll
      for (int u = 0; u < 4; ++u) {
        int j = 16 * u + ln;
        if (j >= MT)      S[t][u][r] = -1e30f;   // pad keys
        else if (i < NQ)  S[t][u][r] += mrow[i * MT + j];
      }
    }
  }

  // ---- softmax in registers; store unnormalized P (bf16) to LDS ------------
  float rsumv[4][4];
#pragma unroll
  for (int t = 0; t < 4; ++t) {
#pragma unroll
    for (int r = 0; r < 4; ++r) {
      float mx = fmaxf(fmaxf(S[t][0][r], S[t][1][r]), fmaxf(S[t][2][r], S[t][3][r]));
#pragma unroll
      for (int s = 1; s < 16; s <<= 1) mx = fmaxf(mx, __shfl_xor(mx, s, 16));
      int m  = 16 * t + 4 * qd + r;
      int m7 = m & 7;
      float sum = 0.f;
#pragma unroll
      for (int u = 0; u < 4; ++u) {
        float p = exp2f((S[t][u][r] - mx) * 1.4426950408889634f);
        sum += p;
        int c = 16 * u + ln;
        int addr = m * 64 + ((((c >> 3) ^ m7) << 3) | (c & 7));
        sP[wv][addr] = (unsigned short)bf16rn(p);
      }
#pragma unroll
      for (int s = 1; s < 16; s <<= 1) sum += __shfl_xor(sum, s, 16);
      rsumv[t][r] = sum;
    }
  }
  __syncthreads();

  // ---- V fragments (bf16 hi/lo) --------------------------------------------
  short8 vh[2][2], vl[2][2];   // [k-iter][d-tile]
#pragma unroll
  for (int kt = 0; kt < 2; ++kt) {
#pragma unroll
    for (int u2 = 0; u2 < 2; ++u2) {
#pragma unroll
      for (int j = 0; j < 8; ++j) {
        int k  = 32 * kt + 8 * qd + j;
        int d  = 16 * u2 + ln;
        int kc = (k < MT ? k : MT - 1);
        float x = base[(size_t)kc * 768 + 512 + h * HD + d];
        if (k >= MT) x = 0.f;
        uint32_t hi, lo; bsplit(x, hi, lo);
        vh[kt][u2][j] = (short)(unsigned short)hi;
        vl[kt][u2][j] = (short)(unsigned short)lo;
      }
    }
  }

  // ---- PV via MFMA: LDS read IS the A-fragment (bf16, swizzled) ------------
  f32x4 O[4][2];
#pragma unroll
  for (int t = 0; t < 4; ++t)
#pragma unroll
    for (int u2 = 0; u2 < 2; ++u2) O[t][u2] = (f32x4){0.f, 0.f, 0.f, 0.f};

#pragma unroll
  for (int kt = 0; kt < 2; ++kt) {
#pragma unroll
    for (int t = 0; t < 4; ++t) {
      int m = 16 * t + ln;
      int phys = ((4 * kt + qd) ^ (ln & 7));
      short8 ph = *(const short8*)&sP[wv][m * 64 + (phys << 3)];
#pragma unroll
      for (int u2 = 0; u2 < 2; ++u2) {
        f32x4 a = O[t][u2];
        a = __builtin_amdgcn_mfma_f32_16x16x32_bf16(ph, vh[kt][u2], a, 0, 0, 0);
        a = __builtin_amdgcn_mfma_f32_16x16x32_bf16(ph, vl[kt][u2], a, 0, 0, 0);
        O[t][u2] = a;
      }
    }
  }

  // ---- epilogue: normalize + store -----------------------------------------
#pragma unroll
  for (int t = 0; t < 4; ++t) {
#pragma unroll
    for (int r = 0; r < 4; ++r) {
      int row = 16 * t + 4 * qd + r;
      if (row >= NQ) continue;
      float inv = 1.0f / rsumv[t][r];
#pragma unroll
      for (int u2 = 0; u2 < 2; ++u2) {
        int d = 16 * u2 + ln;
        out[(((size_t)b * NQ + row) * NH + h) * HD + d] = O[t][u2][r] * inv;
      }
    }
  }
}

extern "C" void kernel_launch(void* const* d_in, const int* in_sizes, int n_in,
                              void* d_out, int out_size, void* d_ws, size_t ws_size,
                              hipStream_t stream) {
  (void)in_sizes; (void)n_in; (void)ws_size; (void)out_size;
  const float* qkv        = (const float*)d_in[0];
  const float* mask       = (const float*)d_in[1];
  const float* bias_table = (const float*)d_in[2];
  const int*   rel_index  = (const int*)d_in[3];
  float* out = (float*)d_out;
  float* M2  = (float*)d_ws;   // 6.27 MB fused mask+bias scratch

  fuse_mb<<<(M2TOT + 255) / 256, 256, 0, stream>>>(mask, bias_table, rel_index, M2);
  winattn_kernel<<<BWIN * 4, 128, 0, stream>>>(qkv, M2, out);
}